// Round 2
// baseline (231.963 us; speedup 1.0000x reference)
//
#include <hip/hip_runtime.h>

// QLayerNorm (fp32 in / fp32 out): LayerNorm over D=1024 with the reference's
// 4-step fixed-point "sqrt": a = var + 5e-5; l1=(a/a+a)/2; l_{k+1}=(l_k/a + a)/2
// (divisor is ALWAYS a); out = (x-mean)/std * w + b.
// One wave (64 lanes) per row, 16 floats/lane via 4x float4 loads. No LDS.

constexpr int D_DIM = 1024;
constexpr float EPS = 5e-5f;

__global__ __launch_bounds__(256) void qln_kernel(
    const float* __restrict__ x,
    const float* __restrict__ w,
    const float* __restrict__ b,
    float* __restrict__ out,
    int nrows)
{
    const int gtid = blockIdx.x * blockDim.x + threadIdx.x;
    const int row  = gtid >> 6;          // one wave (64 lanes) per row
    const int lane = gtid & 63;
    if (row >= nrows) return;

    const float4* __restrict__ xr = (const float4*)(x + (size_t)row * D_DIM);

    // Each lane: 4 x float4, chunk c covers cols [256c, 256c+256), lane-coalesced.
    float4 v[4];
    float sum = 0.f, sq = 0.f;
#pragma unroll
    for (int c = 0; c < 4; ++c) {
        v[c] = xr[lane + 64 * c];
        sum += (v[c].x + v[c].y) + (v[c].z + v[c].w);
        sq = fmaf(v[c].x, v[c].x, sq);
        sq = fmaf(v[c].y, v[c].y, sq);
        sq = fmaf(v[c].z, v[c].z, sq);
        sq = fmaf(v[c].w, v[c].w, sq);
    }

    // 64-lane butterfly reduction (wave64: 6 steps)
#pragma unroll
    for (int m = 32; m >= 1; m >>= 1) {
        sum += __shfl_xor(sum, m, 64);
        sq  += __shfl_xor(sq,  m, 64);
    }

    const float invD = 1.0f / (float)D_DIM;
    const float mean = sum * invD;
    const float var  = fmaf(-mean, mean, sq * invD);   // E[x^2] - mean^2
    const float a    = var + EPS;

    // Faithful fixed-point iteration (divisor always a, per reference)
    float l = (a / a + a) * 0.5f;        // l1
    l = (l / a + a) * 0.5f;              // l2
    l = (l / a + a) * 0.5f;              // l3
    const float std_ = (l / a + a) * 0.5f;
    const float inv_std = 1.0f / std_;

    const float4* __restrict__ w4 = (const float4*)w;
    const float4* __restrict__ b4 = (const float4*)b;
    float4* __restrict__ orow = (float4*)(out + (size_t)row * D_DIM);

#pragma unroll
    for (int c = 0; c < 4; ++c) {
        const float4 wv = w4[lane + 64 * c];
        const float4 bv = b4[lane + 64 * c];
        float4 ov;
        ov.x = fmaf((v[c].x - mean) * inv_std, wv.x, bv.x);
        ov.y = fmaf((v[c].y - mean) * inv_std, wv.y, bv.y);
        ov.z = fmaf((v[c].z - mean) * inv_std, wv.z, bv.z);
        ov.w = fmaf((v[c].w - mean) * inv_std, wv.w, bv.w);
        orow[lane + 64 * c] = ov;
    }
}

extern "C" void kernel_launch(void* const* d_in, const int* in_sizes, int n_in,
                              void* d_out, int out_size, void* d_ws, size_t ws_size,
                              hipStream_t stream) {
    const float* x = (const float*)d_in[0];
    const float* w = (const float*)d_in[1];
    const float* b = (const float*)d_in[2];
    float* out = (float*)d_out;

    const int nrows = in_sizes[0] / D_DIM;        // 32768 rows
    const int threads = 256;                       // 4 waves -> 4 rows per block
    const int blocks = (nrows * 64) / threads;     // 8192 blocks
    qln_kernel<<<blocks, threads, 0, stream>>>(x, w, b, out, nrows);
}

// Round 4
// 224.303 us; speedup vs baseline: 1.0341x; 1.0341x over previous
//
#include <hip/hip_runtime.h>

// QLayerNorm (fp32 in / fp32 out): LayerNorm over D=1024 with the reference's
// 4-step fixed-point "sqrt": a = var + 5e-5; l1=(a/a+a)/2; l_{k+1}=(l_k/a + a)/2
// (divisor is ALWAYS a); out = (x-mean)/std * w + b.
//
// R3: same as R2 but with clang ext_vector float4 (HIP_vector_type struct is
// rejected by __builtin_nontemporal_*). One wave per TWO rows (ILP on the
// serial reduce/divide chains, w/b registers shared across both rows),
// nontemporal loads/stores for streamed x/out, w/b hoisted early.

constexpr int D_DIM = 1024;
constexpr float EPS = 5e-5f;

typedef float vfloat4 __attribute__((ext_vector_type(4)));

__global__ __launch_bounds__(256) void qln_kernel(
    const float* __restrict__ x,
    const float* __restrict__ w,
    const float* __restrict__ b,
    float* __restrict__ out,
    int nrows)
{
    const int gtid = blockIdx.x * blockDim.x + threadIdx.x;
    const int wid  = gtid >> 6;           // one wave per 2 rows
    const int lane = gtid & 63;
    const int r0 = wid * 2;
    const int r1 = r0 + 1;
    if (r0 >= nrows) return;
    const bool has2 = (r1 < nrows);       // wave-uniform

    const vfloat4* __restrict__ w4 = (const vfloat4*)w;
    const vfloat4* __restrict__ b4 = (const vfloat4*)b;
    const vfloat4* __restrict__ xr0 = (const vfloat4*)(x + (size_t)r0 * D_DIM);
    const vfloat4* __restrict__ xr1 = (const vfloat4*)(x + (size_t)r1 * D_DIM);

    // w/b loads issued first: their L2 latency hides under the butterfly.
    vfloat4 wv[4], bv[4];
#pragma unroll
    for (int c = 0; c < 4; ++c) {
        wv[c] = w4[lane + 64 * c];
        bv[c] = b4[lane + 64 * c];
    }

    // Streamed x: nontemporal (read-once), 16B/lane coalesced.
    vfloat4 v0[4], v1[4];
#pragma unroll
    for (int c = 0; c < 4; ++c)
        v0[c] = __builtin_nontemporal_load(&xr0[lane + 64 * c]);
    if (has2) {
#pragma unroll
        for (int c = 0; c < 4; ++c)
            v1[c] = __builtin_nontemporal_load(&xr1[lane + 64 * c]);
    } else {
#pragma unroll
        for (int c = 0; c < 4; ++c) v1[c] = (vfloat4)(0.f);
    }

    float sum0 = 0.f, sq0 = 0.f, sum1 = 0.f, sq1 = 0.f;
#pragma unroll
    for (int c = 0; c < 4; ++c) {
        sum0 += (v0[c].x + v0[c].y) + (v0[c].z + v0[c].w);
        sq0 = fmaf(v0[c].x, v0[c].x, sq0);
        sq0 = fmaf(v0[c].y, v0[c].y, sq0);
        sq0 = fmaf(v0[c].z, v0[c].z, sq0);
        sq0 = fmaf(v0[c].w, v0[c].w, sq0);
        sum1 += (v1[c].x + v1[c].y) + (v1[c].z + v1[c].w);
        sq1 = fmaf(v1[c].x, v1[c].x, sq1);
        sq1 = fmaf(v1[c].y, v1[c].y, sq1);
        sq1 = fmaf(v1[c].z, v1[c].z, sq1);
        sq1 = fmaf(v1[c].w, v1[c].w, sq1);
    }

    // 64-lane butterfly; two rows' chains interleave (independent).
#pragma unroll
    for (int m = 32; m >= 1; m >>= 1) {
        sum0 += __shfl_xor(sum0, m, 64);
        sq0  += __shfl_xor(sq0,  m, 64);
        sum1 += __shfl_xor(sum1, m, 64);
        sq1  += __shfl_xor(sq1,  m, 64);
    }

    const float invD = 1.0f / (float)D_DIM;
    const float mean0 = sum0 * invD;
    const float mean1 = sum1 * invD;
    const float var0 = fmaf(-mean0, mean0, sq0 * invD);
    const float var1 = fmaf(-mean1, mean1, sq1 * invD);
    const float a0 = var0 + EPS;
    const float a1 = var1 + EPS;

    // Faithful fixed-point iteration (divisor always a); two chains interleave.
    float l0 = (a0 / a0 + a0) * 0.5f;
    float l1 = (a1 / a1 + a1) * 0.5f;
    l0 = (l0 / a0 + a0) * 0.5f;
    l1 = (l1 / a1 + a1) * 0.5f;
    l0 = (l0 / a0 + a0) * 0.5f;
    l1 = (l1 / a1 + a1) * 0.5f;
    const float std0 = (l0 / a0 + a0) * 0.5f;
    const float std1 = (l1 / a1 + a1) * 0.5f;
    const float is0 = 1.0f / std0;
    const float is1 = 1.0f / std1;

    vfloat4* __restrict__ o0 = (vfloat4*)(out + (size_t)r0 * D_DIM);
#pragma unroll
    for (int c = 0; c < 4; ++c) {
        vfloat4 ov;
        ov.x = fmaf((v0[c].x - mean0) * is0, wv[c].x, bv[c].x);
        ov.y = fmaf((v0[c].y - mean0) * is0, wv[c].y, bv[c].y);
        ov.z = fmaf((v0[c].z - mean0) * is0, wv[c].z, bv[c].z);
        ov.w = fmaf((v0[c].w - mean0) * is0, wv[c].w, bv[c].w);
        __builtin_nontemporal_store(ov, &o0[lane + 64 * c]);
    }
    if (has2) {
        vfloat4* __restrict__ o1 = (vfloat4*)(out + (size_t)r1 * D_DIM);
#pragma unroll
        for (int c = 0; c < 4; ++c) {
            vfloat4 ov;
            ov.x = fmaf((v1[c].x - mean1) * is1, wv[c].x, bv[c].x);
            ov.y = fmaf((v1[c].y - mean1) * is1, wv[c].y, bv[c].y);
            ov.z = fmaf((v1[c].z - mean1) * is1, wv[c].z, bv[c].z);
            ov.w = fmaf((v1[c].w - mean1) * is1, wv[c].w, bv[c].w);
            __builtin_nontemporal_store(ov, &o1[lane + 64 * c]);
        }
    }
}

extern "C" void kernel_launch(void* const* d_in, const int* in_sizes, int n_in,
                              void* d_out, int out_size, void* d_ws, size_t ws_size,
                              hipStream_t stream) {
    const float* x = (const float*)d_in[0];
    const float* w = (const float*)d_in[1];
    const float* b = (const float*)d_in[2];
    float* out = (float*)d_out;

    const int nrows = in_sizes[0] / D_DIM;            // 32768 rows
    const int nwaves = (nrows + 1) / 2;               // 2 rows per wave
    const int threads = 256;                           // 4 waves per block
    const int blocks = (nwaves * 64 + threads - 1) / threads;
    qln_kernel<<<blocks, threads, 0, stream>>>(x, w, b, out, nrows);
}